// Round 4
// baseline (7018.875 us; speedup 1.0000x reference)
//
#include <hip/hip_runtime.h>

#define FLT_MAX_C 3.402823466e+38f

typedef __attribute__((ext_vector_type(8))) __bf16 bf16x8;
typedef __attribute__((ext_vector_type(4))) float f32x4;

static __device__ __forceinline__ ushort f2bf(float x) {
    union { float f; unsigned u; } v; v.f = x;
    unsigned r = (v.u + 0x7FFFu + ((v.u >> 16) & 1u)) >> 16;
    return (ushort)r;
}

// ---------------- fp32 GEMM (encoder): C = [relu](A @ W + b) ----------------
// BM=128, BN template (256 or 128), BK=8, 256 threads.
// Microtile 8 x (BN/16): rows {tm4..+3, tm4+64..+67}, cols tn4 + {0..3} + 64q.
// All LDS reads are 16-lane x 16B consecutive (2-way = free) or broadcast.
template<bool RELU, int BN, int TAG>
__global__ __launch_bounds__(256, 2) void gemm_f32(
    const float* __restrict__ A, const float* __restrict__ W,
    const float* __restrict__ bias, float* __restrict__ C,
    int M, int K, int N)
{
    constexpr int NQ  = BN / 64;      // col quads per thread (4 or 2)
    constexpr int NC  = NQ * 4;       // cols per thread (16 or 8)
    constexpr int BF4 = BN / 4;       // float4 per B row (64 or 32)
    constexpr int BI  = (8 * BF4) / 256;  // B stage iters per thread (2 or 1)

    __shared__ float As[8][128];
    __shared__ float Bs[8][BN + 4];
    const int tid = threadIdx.x;
    const int bm = blockIdx.y << 7;
    const int bn = blockIdx.x * BN;

    const int la_row = tid >> 1;          // 0..127
    const int la_k   = (tid & 1) << 2;    // 0 or 4
    const int tm4 = (tid >> 4) << 2;      // 0..60
    const int tn4 = (tid & 15) << 2;      // 0..60

    float acc[8][NC];
    #pragma unroll
    for (int i = 0; i < 8; ++i)
        #pragma unroll
        for (int j = 0; j < NC; ++j) acc[i][j] = 0.f;

    const float* aptr = A + (size_t)(bm + la_row) * K + la_k;

    float4 av = *(const float4*)(aptr);
    float4 bv[BI];
    #pragma unroll
    for (int i = 0; i < BI; ++i) {
        int f = tid + (i << 8);
        int row = f / BF4, col4 = f % BF4;
        bv[i] = *(const float4*)(W + (size_t)row * N + bn + col4 * 4);
    }

    for (int k0 = 0; k0 < K; k0 += 8) {
        __syncthreads();
        As[la_k + 0][la_row] = av.x;
        As[la_k + 1][la_row] = av.y;
        As[la_k + 2][la_row] = av.z;
        As[la_k + 3][la_row] = av.w;
        #pragma unroll
        for (int i = 0; i < BI; ++i) {
            int f = tid + (i << 8);
            int row = f / BF4, col4 = f % BF4;
            *(float4*)(&Bs[row][col4 * 4]) = bv[i];
        }
        __syncthreads();
        if (k0 + 8 < K) {   // prefetch next slab under the compute
            av = *(const float4*)(aptr + k0 + 8);
            #pragma unroll
            for (int i = 0; i < BI; ++i) {
                int f = tid + (i << 8);
                int row = f / BF4, col4 = f % BF4;
                bv[i] = *(const float4*)(W + (size_t)(k0 + 8 + row) * N + bn + col4 * 4);
            }
        }
        #pragma unroll
        for (int kk = 0; kk < 8; ++kk) {
            float a[8], b[NC];
            *(float4*)(a)     = *(const float4*)(&As[kk][tm4]);
            *(float4*)(a + 4) = *(const float4*)(&As[kk][tm4 + 64]);
            #pragma unroll
            for (int q = 0; q < NQ; ++q)
                *(float4*)(b + q * 4) = *(const float4*)(&Bs[kk][tn4 + 64 * q]);
            #pragma unroll
            for (int i = 0; i < 8; ++i)
                #pragma unroll
                for (int j = 0; j < NC; ++j)
                    acc[i][j] = fmaf(a[i], b[j], acc[i][j]);
        }
    }

    float bb[NC];
    #pragma unroll
    for (int q = 0; q < NQ; ++q)
        #pragma unroll
        for (int jj = 0; jj < 4; ++jj)
            bb[q * 4 + jj] = bias[bn + tn4 + 64 * q + jj];

    #pragma unroll
    for (int i = 0; i < 8; ++i) {
        int row = bm + tm4 + (i < 4 ? i : 60 + i);
        float* cp = C + (size_t)row * N + bn + tn4;
        #pragma unroll
        for (int q = 0; q < NQ; ++q) {
            float4 v;
            v.x = acc[i][q * 4 + 0] + bb[q * 4 + 0];
            v.y = acc[i][q * 4 + 1] + bb[q * 4 + 1];
            v.z = acc[i][q * 4 + 2] + bb[q * 4 + 2];
            v.w = acc[i][q * 4 + 3] + bb[q * 4 + 3];
            if (RELU) {
                v.x = fmaxf(v.x, 0.f); v.y = fmaxf(v.y, 0.f);
                v.z = fmaxf(v.z, 0.f); v.w = fmaxf(v.w, 0.f);
            }
            *(float4*)(cp + 64 * q) = v;
        }
    }
}

// ---------------- bf16 MFMA GEMM (decoder) ----------------
template<bool RELU, bool OUTF32, int TAG>
__global__ __launch_bounds__(256) void gemm_bf16(
    const ushort* __restrict__ A,    // [M][K] bf16 bits
    const ushort* __restrict__ Wt,   // [N][K] bf16 bits (pre-transposed W)
    const float* __restrict__ bias,
    void* __restrict__ C,            // bf16 [M][N] or f32 [M][N]
    int M, int K, int N)
{
    __shared__ __align__(16) ushort As[128][64];
    __shared__ __align__(16) ushort Bs[128][64];
    const int tid  = threadIdx.x;
    const int lane = tid & 63;
    const int wv   = tid >> 6;
    const int wm   = (wv >> 1) << 6;   // 0 or 64
    const int wn   = (wv & 1) << 6;
    const int bm   = blockIdx.y << 7;
    const int bn   = blockIdx.x << 7;
    const int lr   = lane & 15;
    const int lh   = lane >> 4;        // 0..3

    f32x4 acc[4][4];
    #pragma unroll
    for (int m = 0; m < 4; ++m)
        #pragma unroll
        for (int n = 0; n < 4; ++n) acc[m][n] = (f32x4){0.f, 0.f, 0.f, 0.f};

    for (int k0 = 0; k0 < K; k0 += 64) {
        __syncthreads();
        #pragma unroll
        for (int i = 0; i < 4; ++i) {
            const int c    = wv * 4 + i;          // chunk 0..15 (8 rows each)
            const int boff = c * 1024 + lane * 16;
            const int r    = boff >> 7;           // tile row
            const int cb   = boff & 127;          // byte col within 128B row
            const char* sa = (const char*)A  + (((size_t)(bm + r) * K + k0) << 1) + cb;
            const char* sb = (const char*)Wt + (((size_t)(bn + r) * K + k0) << 1) + cb;
            __builtin_amdgcn_global_load_lds((const void*)sa, (void*)(&As[0][0] + c * 512), 16, 0, 0);
            __builtin_amdgcn_global_load_lds((const void*)sb, (void*)(&Bs[0][0] + c * 512), 16, 0, 0);
        }
        __syncthreads();
        #pragma unroll
        for (int kk = 0; kk < 64; kk += 32) {
            bf16x8 af[4], bfr[4];
            #pragma unroll
            for (int m = 0; m < 4; ++m)
                af[m] = *(const bf16x8*)&As[wm + m * 16 + lr][kk + lh * 8];
            #pragma unroll
            for (int n = 0; n < 4; ++n)
                bfr[n] = *(const bf16x8*)&Bs[wn + n * 16 + lr][kk + lh * 8];
            #pragma unroll
            for (int m = 0; m < 4; ++m)
                #pragma unroll
                for (int n = 0; n < 4; ++n)
                    acc[m][n] = __builtin_amdgcn_mfma_f32_16x16x32_bf16(
                        af[m], bfr[n], acc[m][n], 0, 0, 0);
        }
    }

    // epilogue: C/D mapping col = lane&15, row = (lane>>4)*4 + i
    #pragma unroll
    for (int n = 0; n < 4; ++n) {
        const int col = bn + wn + n * 16 + lr;
        const float bcol = bias[col];
        #pragma unroll
        for (int m = 0; m < 4; ++m) {
            #pragma unroll
            for (int i = 0; i < 4; ++i) {
                const int row = bm + wm + m * 16 + lh * 4 + i;
                float v = acc[m][n][i] + bcol;
                if (RELU) v = fmaxf(v, 0.f);
                if (OUTF32) ((float*)C)[(size_t)row * N + col] = v;
                else        ((ushort*)C)[(size_t)row * N + col] = f2bf(v);
            }
        }
    }
}

// ---------------- weight convert+transpose: W[K][N] f32 -> Wt[N][K] bf16 ----
__global__ __launch_bounds__(256) void wt_convert(
    const float* __restrict__ W, ushort* __restrict__ Wt, int K, int N)
{
    __shared__ ushort t[64][65];
    const int kb = blockIdx.y << 6, nb = blockIdx.x << 6;
    const int c  = threadIdx.x & 63;
    const int r0 = (threadIdx.x >> 6) << 4;
    #pragma unroll
    for (int i = 0; i < 16; ++i)
        t[r0 + i][c] = f2bf(W[(size_t)(kb + r0 + i) * N + nb + c]);
    __syncthreads();
    #pragma unroll
    for (int i = 0; i < 16; ++i)
        Wt[(size_t)(nb + r0 + i) * K + kb + c] = t[c][r0 + i];
}

// ---------------- codebook squared norms ----------------
__global__ __launch_bounds__(256) void cbsq_kernel(
    const float* __restrict__ cb, float* __restrict__ cbsq)
{
    int k = blockIdx.x * 256 + threadIdx.x;
    const float* r = cb + ((size_t)k << 7);
    float s = 0.f;
    #pragma unroll 8
    for (int d = 0; d < 128; ++d) s = fmaf(r[d], r[d], s);
    cbsq[k] = s;
}

// ---------------- residual quantization: row-in-lane, register residue ----
// Block = 256 thr = 4 waves; lane l of every wave owns row = blk*64 + l.
// Wave w scans codes [256w, 256w+256). Codebook row address is wave-uniform.
// Zero LDS in the hot loop; 4-candidate merge per row at depth end.
__global__ __launch_bounds__(256, 2) void quant_kernel(
    const float* __restrict__ z, const float* __restrict__ cb,
    const float* __restrict__ cbsq, ushort* __restrict__ zhat_bf,
    float* __restrict__ codes)
{
    __shared__ float sd[4][64];
    __shared__ int   si[4][64];

    const int lane = threadIdx.x & 63;
    const int wv   = threadIdx.x >> 6;
    const size_t row = (size_t)blockIdx.x * 64 + lane;

    const float4* zr = (const float4*)(z + row * 128);
    float4 r[32];
    #pragma unroll
    for (int i = 0; i < 32; ++i) r[i] = zr[i];

    for (int t = 0; t < 3; ++t) {
        // rr = ||r||^2 (4 chains)
        float4 rr4 = {0.f, 0.f, 0.f, 0.f};
        #pragma unroll
        for (int i = 0; i < 32; ++i) {
            rr4.x = fmaf(r[i].x, r[i].x, rr4.x);
            rr4.y = fmaf(r[i].y, r[i].y, rr4.y);
            rr4.z = fmaf(r[i].z, r[i].z, rr4.z);
            rr4.w = fmaf(r[i].w, r[i].w, rr4.w);
        }
        const float rr = (rr4.x + rr4.y) + (rr4.z + rr4.w);

        float bd = FLT_MAX_C; int bi = 0;
        const int kbeg = wv << 8;
        for (int k = kbeg; k < kbeg + 256; ++k) {
            const float4* c4 = (const float4*)(cb + ((size_t)k << 7));
            float4 a4 = {0.f, 0.f, 0.f, 0.f};
            #pragma unroll
            for (int i = 0; i < 32; ++i) {
                float4 cv = c4[i];
                a4.x = fmaf(r[i].x, cv.x, a4.x);
                a4.y = fmaf(r[i].y, cv.y, a4.y);
                a4.z = fmaf(r[i].z, cv.z, a4.z);
                a4.w = fmaf(r[i].w, cv.w, a4.w);
            }
            float dot  = (a4.x + a4.y) + (a4.z + a4.w);
            float dist = (rr + cbsq[k]) - 2.f * dot;
            if (dist < bd) { bd = dist; bi = k; }
        }
        sd[wv][lane] = bd; si[wv][lane] = bi;
        __syncthreads();
        float d = sd[0][lane]; int bidx = si[0][lane];
        #pragma unroll
        for (int w = 1; w < 4; ++w) {
            float dw = sd[w][lane]; int iw = si[w][lane];
            if (dw < d) { d = dw; bidx = iw; }  // ties keep lower wave = lower idx
        }
        __syncthreads();

        if (wv == 0) codes[row * 3 + t] = (float)bidx;

        const float4* cbest = (const float4*)(cb + ((size_t)bidx << 7));
        #pragma unroll
        for (int i = 0; i < 32; ++i) {
            float4 cv = cbest[i];
            r[i].x -= cv.x; r[i].y -= cv.y; r[i].z -= cv.z; r[i].w -= cv.w;
        }
    }

    // zhat = z - r_final (all waves hold identical r; split dims across waves)
    ushort* zrow = zhat_bf + row * 128;
    #pragma unroll
    for (int i = 0; i < 8; ++i) {
        const int idx = (wv << 3) + i;
        float4 zv = zr[idx];
        ushort4 o;
        o.x = f2bf(zv.x - r[idx].x); o.y = f2bf(zv.y - r[idx].y);
        o.z = f2bf(zv.z - r[idx].z); o.w = f2bf(zv.w - r[idx].w);
        ((ushort4*)zrow)[idx] = o;
    }
}

extern "C" void kernel_launch(void* const* d_in, const int* in_sizes, int n_in,
                              void* d_out, int out_size, void* d_ws, size_t ws_size,
                              hipStream_t stream)
{
    const float* x   = (const float*)d_in[0];
    const float* eW1 = (const float*)d_in[1];
    const float* eb1 = (const float*)d_in[2];
    const float* eW2 = (const float*)d_in[3];
    const float* eb2 = (const float*)d_in[4];
    const float* eW3 = (const float*)d_in[5];
    const float* eb3 = (const float*)d_in[6];
    const float* eW4 = (const float*)d_in[7];
    const float* eb4 = (const float*)d_in[8];
    const float* dW1 = (const float*)d_in[9];
    const float* db1 = (const float*)d_in[10];
    const float* dW2 = (const float*)d_in[11];
    const float* db2 = (const float*)d_in[12];
    const float* dW3 = (const float*)d_in[13];
    const float* db3 = (const float*)d_in[14];
    const float* dW4 = (const float*)d_in[15];
    const float* db4 = (const float*)d_in[16];
    const float* cb  = (const float*)d_in[17];

    float* out   = (float*)d_out;
    float* codes = out + (size_t)32768 * 768;

    // ---- workspace layout: [dec Wt bf16 | cbsq | per-chunk activations] ----
    ushort* Wt1 = (ushort*)d_ws;                       // 2048 x 128
    ushort* Wt2 = Wt1 + (size_t)2048 * 128;            // 1024 x 2048
    ushort* Wt3 = Wt2 + (size_t)1024 * 2048;           // 512 x 1024
    ushort* Wt4 = Wt3 + (size_t)512 * 1024;            // 768 x 512
    float*  sq  = (float*)(Wt4 + (size_t)768 * 512);   // 1024
    float*  act = sq + 1024;
    const size_t fixed_b = (char*)act - (char*)d_ws;

    int mc = 32768;                                    // chunk rows
    while (mc > 1024) {
        if (fixed_b + (size_t)mc * 15104 <= ws_size) break;
        mc >>= 1;
    }

    float*  R1  = act;                         // mc x 2048 f32
    float*  R2  = R1 + (size_t)mc * 2048;      // mc x 1024 f32
    float*  R3  = R2 + (size_t)mc * 1024;      // mc x 512  f32
    float*  RZ  = R3 + (size_t)mc * 512;       // mc x 128  f32
    ushort* ZHb = (ushort*)(RZ + (size_t)mc * 128);  // mc x 128 bf16
    ushort* D1  = (ushort*)R1;                 // mc x 2048 bf16 (aliases R1)
    ushort* D2  = (ushort*)R2;                 // mc x 1024 bf16
    ushort* D3  = (ushort*)R3;                 // mc x 512  bf16

    // one-time per-launch prep
    wt_convert<<<dim3(2048 / 64, 128 / 64), 256, 0, stream>>>(dW1, Wt1, 128, 2048);
    wt_convert<<<dim3(1024 / 64, 2048 / 64), 256, 0, stream>>>(dW2, Wt2, 2048, 1024);
    wt_convert<<<dim3(512 / 64, 1024 / 64), 256, 0, stream>>>(dW3, Wt3, 1024, 512);
    wt_convert<<<dim3(768 / 64, 512 / 64), 256, 0, stream>>>(dW4, Wt4, 512, 768);
    cbsq_kernel<<<4, 256, 0, stream>>>(cb, sq);

    const int mg = mc >> 7;
    for (int r0 = 0; r0 < 32768; r0 += mc) {
        const float* xi     = x     + (size_t)r0 * 768;
        float*       outi   = out   + (size_t)r0 * 768;
        float*       codesi = codes + (size_t)r0 * 3;
        // encoder (fp32 exact-class: codes depend on z)
        gemm_f32<true , 256, 1><<<dim3( 8, mg), 256, 0, stream>>>(xi, eW1, eb1, R1, mc, 768,  2048);
        gemm_f32<true , 256, 2><<<dim3( 4, mg), 256, 0, stream>>>(R1, eW2, eb2, R2, mc, 2048, 1024);
        gemm_f32<true , 256, 3><<<dim3( 2, mg), 256, 0, stream>>>(R2, eW3, eb3, R3, mc, 1024, 512);
        gemm_f32<false, 128, 4><<<dim3( 1, mg), 256, 0, stream>>>(R3, eW4, eb4, RZ, mc, 512,  128);
        // residual quantization (fp32 exact formula), emits bf16 z_hat
        quant_kernel<<<mc >> 6, 256, 0, stream>>>(RZ, cb, sq, ZHb, codesi);
        // decoder in bf16 MFMA (tolerance is generous)
        gemm_bf16<true , false, 5><<<dim3(16, mg), 256, 0, stream>>>(ZHb, Wt1, db1, D1,   mc, 128,  2048);
        gemm_bf16<true , false, 6><<<dim3( 8, mg), 256, 0, stream>>>(D1,  Wt2, db2, D2,   mc, 2048, 1024);
        gemm_bf16<true , false, 7><<<dim3( 4, mg), 256, 0, stream>>>(D2,  Wt3, db3, D3,   mc, 1024, 512);
        gemm_bf16<false, true , 8><<<dim3( 6, mg), 256, 0, stream>>>(D3,  Wt4, db4, outi, mc, 512,  768);
    }
}

// Round 5
// 4420.620 us; speedup vs baseline: 1.5878x; 1.5878x over previous
//
#include <hip/hip_runtime.h>

#define FLT_MAX_C 3.402823466e+38f

typedef __attribute__((ext_vector_type(8))) __bf16 bf16x8;
typedef __attribute__((ext_vector_type(4))) float f32x4;

static __device__ __forceinline__ ushort f2bf(float x) {
    union { float f; unsigned u; } v; v.f = x;
    unsigned r = (v.u + 0x7FFFu + ((v.u >> 16) & 1u)) >> 16;
    return (ushort)r;
}

// ---------------- fp32 GEMM (encoder): C = [relu](A @ W + b) ----------------
// R3-proven version: 128x128 tile, BK=8, 256 threads, 8x8 micro-tile in
// split-halves layout (rows {tm4..+3, tm4+64..+67}, cols same) -> LDS reads
// are 16B-consecutive per 16-lane group (2-way = free) or broadcast.
template<bool RELU, int TAG>
__global__ __launch_bounds__(256) void gemm_f32(
    const float* __restrict__ A, const float* __restrict__ W,
    const float* __restrict__ bias, float* __restrict__ C,
    int M, int K, int N)
{
    __shared__ float As[8][128];
    __shared__ float Bs[8][132];
    const int tid = threadIdx.x;
    const int bm = blockIdx.y << 7;
    const int bn = blockIdx.x << 7;

    const int la_row = tid >> 1;          // 0..127
    const int la_k   = (tid & 1) << 2;    // 0 or 4
    const int lb_row = tid >> 5;          // 0..7
    const int lb_col = (tid & 31) << 2;   // 0..124
    const int tm4 = (tid >> 4) << 2;      // 0..60
    const int tn4 = (tid & 15) << 2;      // 0..60

    float acc[8][8];
    #pragma unroll
    for (int i = 0; i < 8; ++i)
        #pragma unroll
        for (int j = 0; j < 8; ++j) acc[i][j] = 0.f;

    const float* aptr = A + (size_t)(bm + la_row) * K + la_k;
    const float* bptr = W + (size_t)lb_row * N + bn + lb_col;

    float4 av = *(const float4*)(aptr);
    float4 bv = *(const float4*)(bptr);

    for (int k0 = 0; k0 < K; k0 += 8) {
        __syncthreads();
        As[la_k + 0][la_row] = av.x;
        As[la_k + 1][la_row] = av.y;
        As[la_k + 2][la_row] = av.z;
        As[la_k + 3][la_row] = av.w;
        *(float4*)(&Bs[lb_row][lb_col]) = bv;
        __syncthreads();
        if (k0 + 8 < K) {   // prefetch next slab under the compute
            av = *(const float4*)(aptr + k0 + 8);
            bv = *(const float4*)(bptr + (size_t)(k0 + 8) * N);
        }
        #pragma unroll
        for (int kk = 0; kk < 8; ++kk) {
            float a[8], b[8];
            *(float4*)(a)     = *(const float4*)(&As[kk][tm4]);
            *(float4*)(a + 4) = *(const float4*)(&As[kk][tm4 + 64]);
            *(float4*)(b)     = *(const float4*)(&Bs[kk][tn4]);
            *(float4*)(b + 4) = *(const float4*)(&Bs[kk][tn4 + 64]);
            #pragma unroll
            for (int i = 0; i < 8; ++i)
                #pragma unroll
                for (int j = 0; j < 8; ++j)
                    acc[i][j] = fmaf(a[i], b[j], acc[i][j]);
        }
    }

    float bv0[8];
    #pragma unroll
    for (int j = 0; j < 8; ++j)
        bv0[j] = bias[bn + tn4 + (j < 4 ? j : 60 + j)];

    #pragma unroll
    for (int i = 0; i < 8; ++i) {
        int row = bm + tm4 + (i < 4 ? i : 60 + i);
        float* cp = C + (size_t)row * N + bn + tn4;
        float4 v0, v1;
        v0.x = acc[i][0] + bv0[0]; v0.y = acc[i][1] + bv0[1];
        v0.z = acc[i][2] + bv0[2]; v0.w = acc[i][3] + bv0[3];
        v1.x = acc[i][4] + bv0[4]; v1.y = acc[i][5] + bv0[5];
        v1.z = acc[i][6] + bv0[6]; v1.w = acc[i][7] + bv0[7];
        if (RELU) {
            v0.x = fmaxf(v0.x, 0.f); v0.y = fmaxf(v0.y, 0.f);
            v0.z = fmaxf(v0.z, 0.f); v0.w = fmaxf(v0.w, 0.f);
            v1.x = fmaxf(v1.x, 0.f); v1.y = fmaxf(v1.y, 0.f);
            v1.z = fmaxf(v1.z, 0.f); v1.w = fmaxf(v1.w, 0.f);
        }
        *(float4*)(cp) = v0;
        *(float4*)(cp + 64) = v1;
    }
}

// ---------------- bf16 MFMA GEMM (decoder) ----------------
template<bool RELU, bool OUTF32, int TAG>
__global__ __launch_bounds__(256) void gemm_bf16(
    const ushort* __restrict__ A,    // [M][K] bf16 bits
    const ushort* __restrict__ Wt,   // [N][K] bf16 bits (pre-transposed W)
    const float* __restrict__ bias,
    void* __restrict__ C,            // bf16 [M][N] or f32 [M][N]
    int M, int K, int N)
{
    __shared__ __align__(16) ushort As[128][64];
    __shared__ __align__(16) ushort Bs[128][64];
    const int tid  = threadIdx.x;
    const int lane = tid & 63;
    const int wv   = tid >> 6;
    const int wm   = (wv >> 1) << 6;   // 0 or 64
    const int wn   = (wv & 1) << 6;
    const int bm   = blockIdx.y << 7;
    const int bn   = blockIdx.x << 7;
    const int lr   = lane & 15;
    const int lh   = lane >> 4;        // 0..3

    f32x4 acc[4][4];
    #pragma unroll
    for (int m = 0; m < 4; ++m)
        #pragma unroll
        for (int n = 0; n < 4; ++n) acc[m][n] = (f32x4){0.f, 0.f, 0.f, 0.f};

    for (int k0 = 0; k0 < K; k0 += 64) {
        __syncthreads();
        #pragma unroll
        for (int i = 0; i < 4; ++i) {
            const int c    = wv * 4 + i;          // chunk 0..15 (8 rows each)
            const int boff = c * 1024 + lane * 16;
            const int r    = boff >> 7;           // tile row
            const int cbt  = boff & 127;          // byte col within 128B row
            const char* sa = (const char*)A  + (((size_t)(bm + r) * K + k0) << 1) + cbt;
            const char* sb = (const char*)Wt + (((size_t)(bn + r) * K + k0) << 1) + cbt;
            __builtin_amdgcn_global_load_lds((const void*)sa, (void*)(&As[0][0] + c * 512), 16, 0, 0);
            __builtin_amdgcn_global_load_lds((const void*)sb, (void*)(&Bs[0][0] + c * 512), 16, 0, 0);
        }
        __syncthreads();
        #pragma unroll
        for (int kk = 0; kk < 64; kk += 32) {
            bf16x8 af[4], bfr[4];
            #pragma unroll
            for (int m = 0; m < 4; ++m)
                af[m] = *(const bf16x8*)&As[wm + m * 16 + lr][kk + lh * 8];
            #pragma unroll
            for (int n = 0; n < 4; ++n)
                bfr[n] = *(const bf16x8*)&Bs[wn + n * 16 + lr][kk + lh * 8];
            #pragma unroll
            for (int m = 0; m < 4; ++m)
                #pragma unroll
                for (int n = 0; n < 4; ++n)
                    acc[m][n] = __builtin_amdgcn_mfma_f32_16x16x32_bf16(
                        af[m], bfr[n], acc[m][n], 0, 0, 0);
        }
    }

    // epilogue: C/D mapping col = lane&15, row = (lane>>4)*4 + i
    #pragma unroll
    for (int n = 0; n < 4; ++n) {
        const int col = bn + wn + n * 16 + lr;
        const float bcol = bias[col];
        #pragma unroll
        for (int m = 0; m < 4; ++m) {
            #pragma unroll
            for (int i = 0; i < 4; ++i) {
                const int row = bm + wm + m * 16 + lh * 4 + i;
                float v = acc[m][n][i] + bcol;
                if (RELU) v = fmaxf(v, 0.f);
                if (OUTF32) ((float*)C)[(size_t)row * N + col] = v;
                else        ((ushort*)C)[(size_t)row * N + col] = f2bf(v);
            }
        }
    }
}

// ---------------- weight convert+transpose: W[K][N] f32 -> Wt[N][K] bf16 ----
__global__ __launch_bounds__(256) void wt_convert(
    const float* __restrict__ W, ushort* __restrict__ Wt, int K, int N)
{
    __shared__ ushort t[64][65];
    const int kb = blockIdx.y << 6, nb = blockIdx.x << 6;
    const int c  = threadIdx.x & 63;
    const int r0 = (threadIdx.x >> 6) << 4;
    #pragma unroll
    for (int i = 0; i < 16; ++i)
        t[r0 + i][c] = f2bf(W[(size_t)(kb + r0 + i) * N + nb + c]);
    __syncthreads();
    #pragma unroll
    for (int i = 0; i < 16; ++i)
        Wt[(size_t)(nb + r0 + i) * K + kb + c] = t[c][r0 + i];
}

// ---------------- codebook squared norms ----------------
__global__ __launch_bounds__(256) void cbsq_kernel(
    const float* __restrict__ cb, float* __restrict__ cbsq)
{
    int k = blockIdx.x * 256 + threadIdx.x;
    const float* r = cb + ((size_t)k << 7);
    float s = 0.f;
    #pragma unroll 8
    for (int d = 0; d < 128; ++d) s = fmaf(r[d], r[d], s);
    cbsq[k] = s;
}

// ---------------- residual quantization v3 ----------------
// Row-in-lane, residue in registers; codebook staged to per-wave LDS regions
// via global_load_lds, double-buffered 16-code chunks with counted vmcnt.
// Wave w scans codes [256w, 256w+256); LDS merge keeps numpy first-min.
__global__ __launch_bounds__(256, 2) void quant_kernel(
    const float* __restrict__ z, const float* __restrict__ cb,
    const float* __restrict__ cbsq, ushort* __restrict__ zhat_bf,
    float* __restrict__ codes)
{
    __shared__ __align__(16) float cbl[2][4][16 * 128];  // 64 KiB
    __shared__ float sd[4][64];
    __shared__ int   si[4][64];

    const int lane = threadIdx.x & 63;
    const int wv   = threadIdx.x >> 6;
    const size_t row = (size_t)blockIdx.x * 64 + lane;
    const int kbeg = wv << 8;

    const float4* zr = (const float4*)(z + row * 128);
    float4 r[32];
    #pragma unroll
    for (int i = 0; i < 32; ++i) r[i] = zr[i];

    // cbsq for this wave's 256 codes, 4 per lane (served via shuffle)
    float mycb[4];
    #pragma unroll
    for (int j = 0; j < 4; ++j) mycb[j] = cbsq[kbeg + (j << 6) + lane];

    // stage chunk c (16 codes) of this wave's range into buffer b
    auto stage = [&](int c, int b) {
        const float* src = cb + ((size_t)(kbeg + (c << 4)) << 7);
        float* dst = &cbl[b][wv][0];
        #pragma unroll
        for (int i = 0; i < 8; ++i) {
            __builtin_amdgcn_global_load_lds(
                (const void*)(src + i * 256 + lane * 4),
                (void*)(dst + i * 256), 16, 0, 0);
        }
    };

    for (int t = 0; t < 3; ++t) {
        float4 rr4 = {0.f, 0.f, 0.f, 0.f};
        #pragma unroll
        for (int i = 0; i < 32; ++i) {
            rr4.x = fmaf(r[i].x, r[i].x, rr4.x);
            rr4.y = fmaf(r[i].y, r[i].y, rr4.y);
            rr4.z = fmaf(r[i].z, r[i].z, rr4.z);
            rr4.w = fmaf(r[i].w, r[i].w, rr4.w);
        }
        const float rr = (rr4.x + rr4.y) + (rr4.z + rr4.w);

        stage(0, 0);
        float bd = FLT_MAX_C; int bi = 0;
        for (int c = 0; c < 16; ++c) {
            if (c < 15) {
                stage(c + 1, (c + 1) & 1);
                asm volatile("s_waitcnt vmcnt(8)" ::: "memory");
            } else {
                asm volatile("s_waitcnt vmcnt(0)" ::: "memory");
            }
            const float* buf = cbl[c & 1][wv];
            for (int tt = 0; tt < 16; ++tt) {
                const float4* c4 = (const float4*)(buf + tt * 128);
                float4 a4 = {0.f, 0.f, 0.f, 0.f};
                #pragma unroll
                for (int i = 0; i < 32; ++i) {
                    float4 cv = c4[i];
                    a4.x = fmaf(r[i].x, cv.x, a4.x);
                    a4.y = fmaf(r[i].y, cv.y, a4.y);
                    a4.z = fmaf(r[i].z, cv.z, a4.z);
                    a4.w = fmaf(r[i].w, cv.w, a4.w);
                }
                float dot = (a4.x + a4.y) + (a4.z + a4.w);
                const int q = (c << 4) + tt;
                float cs = __shfl(mycb[q >> 6], q & 63);
                float dist = (rr + cs) - 2.f * dot;
                if (dist < bd) { bd = dist; bi = kbeg + q; }
            }
        }
        sd[wv][lane] = bd; si[wv][lane] = bi;
        __syncthreads();
        float d = sd[0][lane]; int bidx = si[0][lane];
        #pragma unroll
        for (int w = 1; w < 4; ++w) {
            float dw = sd[w][lane]; int iw = si[w][lane];
            if (dw < d) { d = dw; bidx = iw; }  // strict < keeps lower wave/idx
        }
        __syncthreads();

        if (wv == 0) codes[row * 3 + t] = (float)bidx;

        const float4* cbest = (const float4*)(cb + ((size_t)bidx << 7));
        #pragma unroll
        for (int i = 0; i < 32; ++i) {
            float4 cv = cbest[i];
            r[i].x -= cv.x; r[i].y -= cv.y; r[i].z -= cv.z; r[i].w -= cv.w;
        }
    }

    // zhat = z - r_final (all waves hold identical r; split dims across waves)
    ushort* zrow = zhat_bf + row * 128;
    #pragma unroll
    for (int i = 0; i < 8; ++i) {
        const int idx = (wv << 3) + i;
        float4 zv = zr[idx];
        ushort4 o;
        o.x = f2bf(zv.x - r[idx].x); o.y = f2bf(zv.y - r[idx].y);
        o.z = f2bf(zv.z - r[idx].z); o.w = f2bf(zv.w - r[idx].w);
        ((ushort4*)zrow)[idx] = o;
    }
}

extern "C" void kernel_launch(void* const* d_in, const int* in_sizes, int n_in,
                              void* d_out, int out_size, void* d_ws, size_t ws_size,
                              hipStream_t stream)
{
    const float* x   = (const float*)d_in[0];
    const float* eW1 = (const float*)d_in[1];
    const float* eb1 = (const float*)d_in[2];
    const float* eW2 = (const float*)d_in[3];
    const float* eb2 = (const float*)d_in[4];
    const float* eW3 = (const float*)d_in[5];
    const float* eb3 = (const float*)d_in[6];
    const float* eW4 = (const float*)d_in[7];
    const float* eb4 = (const float*)d_in[8];
    const float* dW1 = (const float*)d_in[9];
    const float* db1 = (const float*)d_in[10];
    const float* dW2 = (const float*)d_in[11];
    const float* db2 = (const float*)d_in[12];
    const float* dW3 = (const float*)d_in[13];
    const float* db3 = (const float*)d_in[14];
    const float* dW4 = (const float*)d_in[15];
    const float* db4 = (const float*)d_in[16];
    const float* cb  = (const float*)d_in[17];

    float* out   = (float*)d_out;
    float* codes = out + (size_t)32768 * 768;

    // ---- workspace layout: [dec Wt bf16 | cbsq | per-chunk activations] ----
    ushort* Wt1 = (ushort*)d_ws;                       // 2048 x 128
    ushort* Wt2 = Wt1 + (size_t)2048 * 128;            // 1024 x 2048
    ushort* Wt3 = Wt2 + (size_t)1024 * 2048;           // 512 x 1024
    ushort* Wt4 = Wt3 + (size_t)512 * 1024;            // 768 x 512
    float*  sq  = (float*)(Wt4 + (size_t)768 * 512);   // 1024
    float*  act = sq + 1024;
    const size_t fixed_b = (char*)act - (char*)d_ws;

    int mc = 32768;                                    // chunk rows
    while (mc > 1024) {
        if (fixed_b + (size_t)mc * 15104 <= ws_size) break;
        mc >>= 1;
    }

    float*  R1  = act;                         // mc x 2048 f32
    float*  R2  = R1 + (size_t)mc * 2048;      // mc x 1024 f32
    float*  R3  = R2 + (size_t)mc * 1024;      // mc x 512  f32
    float*  RZ  = R3 + (size_t)mc * 512;       // mc x 128  f32
    ushort* ZHb = (ushort*)(RZ + (size_t)mc * 128);  // mc x 128 bf16
    ushort* D1  = (ushort*)R1;                 // mc x 2048 bf16 (aliases R1)
    ushort* D2  = (ushort*)R2;                 // mc x 1024 bf16
    ushort* D3  = (ushort*)R3;                 // mc x 512  bf16

    // one-time per-launch prep
    wt_convert<<<dim3(2048 / 64, 128 / 64), 256, 0, stream>>>(dW1, Wt1, 128, 2048);
    wt_convert<<<dim3(1024 / 64, 2048 / 64), 256, 0, stream>>>(dW2, Wt2, 2048, 1024);
    wt_convert<<<dim3(512 / 64, 1024 / 64), 256, 0, stream>>>(dW3, Wt3, 1024, 512);
    wt_convert<<<dim3(768 / 64, 512 / 64), 256, 0, stream>>>(dW4, Wt4, 512, 768);
    cbsq_kernel<<<4, 256, 0, stream>>>(cb, sq);

    const int mg = mc >> 7;
    for (int r0 = 0; r0 < 32768; r0 += mc) {
        const float* xi     = x     + (size_t)r0 * 768;
        float*       outi   = out   + (size_t)r0 * 768;
        float*       codesi = codes + (size_t)r0 * 3;
        // encoder (fp32 exact-class: codes depend on z)
        gemm_f32<true , 1><<<dim3(16, mg), 256, 0, stream>>>(xi, eW1, eb1, R1, mc, 768,  2048);
        gemm_f32<true , 2><<<dim3( 8, mg), 256, 0, stream>>>(R1, eW2, eb2, R2, mc, 2048, 1024);
        gemm_f32<true , 3><<<dim3( 4, mg), 256, 0, stream>>>(R2, eW3, eb3, R3, mc, 1024, 512);
        gemm_f32<false, 4><<<dim3( 1, mg), 256, 0, stream>>>(R3, eW4, eb4, RZ, mc, 512,  128);
        // residual quantization (fp32 exact formula), emits bf16 z_hat
        quant_kernel<<<mc >> 6, 256, 0, stream>>>(RZ, cb, sq, ZHb, codesi);
        // decoder in bf16 MFMA (tolerance is generous)
        gemm_bf16<true , false, 5><<<dim3(16, mg), 256, 0, stream>>>(ZHb, Wt1, db1, D1,   mc, 128,  2048);
        gemm_bf16<true , false, 6><<<dim3( 8, mg), 256, 0, stream>>>(D1,  Wt2, db2, D2,   mc, 2048, 1024);
        gemm_bf16<true , false, 7><<<dim3( 4, mg), 256, 0, stream>>>(D2,  Wt3, db3, D3,   mc, 1024, 512);
        gemm_bf16<false, true , 8><<<dim3( 6, mg), 256, 0, stream>>>(D3,  Wt4, db4, outi, mc, 512,  768);
    }
}